// Round 9
// baseline (230.465 us; speedup 1.0000x reference)
//
#include <hip/hip_runtime.h>
#include <hip/hip_bf16.h>

#define N0C 360448
#define N1C 22528
#define N2C 2048

typedef __attribute__((ext_vector_type(8))) short bf16x8;
typedef __attribute__((ext_vector_type(4))) float f32x4;

__device__ __forceinline__ short f2bf(float f) {
    union { float f; unsigned u; } x; x.f = f;
    unsigned r = x.u + 0x7fff + ((x.u >> 16) & 1);   // RNE
    return (short)(r >> 16);
}
__device__ __forceinline__ float bf2f(unsigned short u) {
    union { unsigned u; float f; } x; x.u = ((unsigned)u) << 16;
    return x.f;
}

// ---------------------------------------------------------------------------
// Prep: Wcat{0,1} bf16 [256][512] = [Wl | Wr] rows; zero hists.
// ---------------------------------------------------------------------------
__global__ __launch_bounds__(256)
void prep_kernel(const float* __restrict__ Wl0, const float* __restrict__ Wr0,
                 const float* __restrict__ Wl1, const float* __restrict__ Wr1,
                 short* __restrict__ Wcat0, short* __restrict__ Wcat1,
                 int* __restrict__ hist0, int* __restrict__ hist1) {
    const int stride = gridDim.x * blockDim.x;
    const int t0 = blockIdx.x * blockDim.x + threadIdx.x;
    for (int i = t0; i < 2 * 256 * 512; i += stride) {
        int layer = i >> 17;
        int r = i & ((1 << 17) - 1);
        int j = r >> 9, k = r & 511;
        const float* Wl = layer ? Wl1 : Wl0;
        const float* Wr = layer ? Wr1 : Wr0;
        float v = (k < 256) ? Wl[j * 256 + k] : Wr[j * 256 + (k - 256)];
        (layer ? Wcat1 : Wcat0)[r] = f2bf(v);
    }
    for (int i = t0; i < N1C + N2C; i += stride) {
        if (i < N1C) hist0[i] = 0; else hist1[i - N1C] = 0;
    }
}

// ---------------------------------------------------------------------------
// CSR build (both layers)
// ---------------------------------------------------------------------------
__global__ void hist_both_kernel(const int* __restrict__ dst0, int E0,
                                 const int* __restrict__ dst1, int E1,
                                 int* __restrict__ hist0, int* __restrict__ hist1) {
    const int stride = gridDim.x * blockDim.x;
    for (int i = blockIdx.x * blockDim.x + threadIdx.x; i < E0 + E1; i += stride) {
        if (i < E0) atomicAdd(&hist0[dst0[i]], 1);
        else        atomicAdd(&hist1[dst1[i - E0]], 1);
    }
}

// Shuffle-based single-block scan: 2 barriers total.
__global__ __launch_bounds__(1024)
void scan_both_kernel(const int* __restrict__ hist0, int* __restrict__ rowptr0,
                      int* __restrict__ cursor0,
                      const int* __restrict__ hist1, int* __restrict__ rowptr1,
                      int* __restrict__ cursor1) {
    __shared__ int wsum[16];
    const int N = (blockIdx.x == 0) ? N1C : N2C;
    const int* hist   = (blockIdx.x == 0) ? hist0 : hist1;
    int* rowptr       = (blockIdx.x == 0) ? rowptr0 : rowptr1;
    int* cursor       = (blockIdx.x == 0) ? cursor0 : cursor1;
    const int tid = threadIdx.x;
    const int lane = tid & 63;
    const int wid = tid >> 6;
    const int per = (N + 1023) >> 10;
    const int start = min(tid * per, N);
    const int end = min(start + per, N);
    int s = 0;
    for (int i = start; i < end; ++i) s += hist[i];
    int incl = s;
#pragma unroll
    for (int d = 1; d < 64; d <<= 1) {
        int t = __shfl_up(incl, d);
        if (lane >= d) incl += t;
    }
    if (lane == 63) wsum[wid] = incl;
    __syncthreads();
    if (wid == 0) {
        int v = (lane < 16) ? wsum[lane] : 0;
#pragma unroll
        for (int d = 1; d < 16; d <<= 1) {
            int t = __shfl_up(v, d);
            if (lane >= d) v += t;
        }
        if (lane < 16) wsum[lane] = v;
    }
    __syncthreads();
    int off = (wid > 0 ? wsum[wid - 1] : 0) + (incl - s);   // exclusive prefix
    for (int i = start; i < end; ++i) {
        rowptr[i] = off;
        cursor[i] = off;
        off += hist[i];
    }
    if (tid == 1023) rowptr[N] = wsum[15];
}

__global__ void fill_both_kernel(const int* __restrict__ src0, const int* __restrict__ dst0, int E0,
                                 const int* __restrict__ src1, const int* __restrict__ dst1, int E1,
                                 int* __restrict__ cursor0, int* __restrict__ eidx0,
                                 int* __restrict__ cursor1, int* __restrict__ eidx1) {
    const int stride = gridDim.x * blockDim.x;
    for (int i = blockIdx.x * blockDim.x + threadIdx.x; i < E0 + E1; i += stride) {
        if (i < E0) {
            int p = atomicAdd(&cursor0[dst0[i]], 1);
            eidx0[p] = src0[i];
        } else {
            int p = atomicAdd(&cursor1[dst1[i - E0]], 1);
            eidx1[p] = src1[i - E0];
        }
    }
}

// ---------------------------------------------------------------------------
// FUSED layer-0: gather-mean(+xcast) into LDS A-tile, then MFMA -> h (bf16),
// dual-writing first N2C rows into Acat1 right half.
// 352 blocks x 4 waves; block owns 64 rows; LDS [64][520] bf16 (padded).
// Gather: wave w handles nodes [rbase+w*16, +16), 8-deep unrolled row reads.
// MFMA: wave w computes its 16 rows x 256 cols (CT=16), A read from LDS once.
// ---------------------------------------------------------------------------
__global__ __launch_bounds__(256)
void sage0_fused_kernel(const float* __restrict__ x, const int* __restrict__ rowptr,
                        const int* __restrict__ eidx, const short* __restrict__ W,
                        const float* __restrict__ bias, short* __restrict__ h,
                        short* __restrict__ Acat1) {
    __shared__ short As[64][520];

    const int tid = threadIdx.x;
    const int wave = tid >> 6;
    const int lane = tid & 63;
    const int rbase = blockIdx.x * 64;
    const int co = lane * 4;

    // ---- phase 1: gather 16 nodes per wave ----
    for (int i = 0; i < 16; ++i) {
        const int lr = wave * 16 + i;
        const int node = rbase + lr;
        const float4 xr = *(const float4*)(x + (size_t)node * 256 + co);
        const int beg = rowptr[node];
        const int end = rowptr[node + 1];
        f32x4 acc = {0.f, 0.f, 0.f, 0.f};
        f32x4 acc2 = {0.f, 0.f, 0.f, 0.f};
        int j = beg;
        for (; j + 7 < end; j += 8) {
            const f32x4 v0 = *(const f32x4*)(x + (size_t)eidx[j    ] * 256 + co);
            const f32x4 v1 = *(const f32x4*)(x + (size_t)eidx[j + 1] * 256 + co);
            const f32x4 v2 = *(const f32x4*)(x + (size_t)eidx[j + 2] * 256 + co);
            const f32x4 v3 = *(const f32x4*)(x + (size_t)eidx[j + 3] * 256 + co);
            const f32x4 v4 = *(const f32x4*)(x + (size_t)eidx[j + 4] * 256 + co);
            const f32x4 v5 = *(const f32x4*)(x + (size_t)eidx[j + 5] * 256 + co);
            const f32x4 v6 = *(const f32x4*)(x + (size_t)eidx[j + 6] * 256 + co);
            const f32x4 v7 = *(const f32x4*)(x + (size_t)eidx[j + 7] * 256 + co);
            acc  += v0 + v1 + v2 + v3;
            acc2 += v4 + v5 + v6 + v7;
        }
        for (; j + 1 < end; j += 2) {
            const f32x4 v0 = *(const f32x4*)(x + (size_t)eidx[j    ] * 256 + co);
            const f32x4 v1 = *(const f32x4*)(x + (size_t)eidx[j + 1] * 256 + co);
            acc += v0 + v1;
        }
        if (j < end)
            acc2 += *(const f32x4*)(x + (size_t)eidx[j] * 256 + co);
        acc += acc2;

        const float sc = 1.0f / fmaxf((float)(end - beg), 1.0f);
        short4 o;
        o.x = f2bf(acc.x * sc); o.y = f2bf(acc.y * sc);
        o.z = f2bf(acc.z * sc); o.w = f2bf(acc.w * sc);
        *(short4*)&As[lr][co] = o;
        short4 xo;
        xo.x = f2bf(xr.x); xo.y = f2bf(xr.y); xo.z = f2bf(xr.z); xo.w = f2bf(xr.w);
        *(short4*)&As[lr][256 + co] = xo;
    }
    __syncthreads();

    // ---- phase 2: MFMA, wave w rows [w*16,+16), all 256 cols (CT=16) ----
    const int lrow = lane & 15;
    const int lk = (lane >> 4) * 8;
    const short* arow = &As[wave * 16 + lrow][lk];
    const short* wbase = W + (size_t)lrow * 512 + lk;

    f32x4 acc[16] = {};
#pragma unroll
    for (int ks = 0; ks < 16; ++ks) {
        bf16x8 a = *(const bf16x8*)(arow + ks * 32);
#pragma unroll
        for (int c = 0; c < 16; ++c) {
            bf16x8 b = *(const bf16x8*)(wbase + (size_t)c * 16 * 512 + ks * 32);
            acc[c] = __builtin_amdgcn_mfma_f32_16x16x32_bf16(a, b, acc[c], 0, 0, 0);
        }
    }

    const int orow = (lane >> 4) * 4;
#pragma unroll
    for (int c = 0; c < 16; ++c) {
        const int col = c * 16 + lrow;
        const float bv = bias[col];
#pragma unroll
        for (int i = 0; i < 4; ++i) {
            const int row = rbase + wave * 16 + orow + i;
            const short hv = f2bf(fmaxf(acc[c][i] + bv, 0.0f));
            h[(size_t)row * 256 + col] = hv;
            if (row < N2C)
                Acat1[(size_t)row * 512 + 256 + col] = hv;
        }
    }
}

// ---------------------------------------------------------------------------
// Layer-1 gather-mean from bf16 h -> left half of Acat1. (2048 waves)
// ---------------------------------------------------------------------------
__global__ __launch_bounds__(256)
void gather1_kernel(const ushort* __restrict__ X, const int* __restrict__ rowptr,
                    const int* __restrict__ eidx, short* __restrict__ Acat, int N) {
    const int wv = (blockIdx.x * 256 + threadIdx.x) >> 6;
    const int lane = threadIdx.x & 63;
    if (wv >= N) return;
    const int beg = rowptr[wv];
    const int end = rowptr[wv + 1];
    float a0 = 0.f, a1 = 0.f, a2 = 0.f, a3 = 0.f;
    int j = beg;
    for (; j + 1 < end; j += 2) {
        int s0 = eidx[j], s1 = eidx[j + 1];
        ushort4 v0 = *(const ushort4*)(X + (size_t)s0 * 256 + lane * 4);
        ushort4 v1 = *(const ushort4*)(X + (size_t)s1 * 256 + lane * 4);
        a0 += bf2f(v0.x) + bf2f(v1.x); a1 += bf2f(v0.y) + bf2f(v1.y);
        a2 += bf2f(v0.z) + bf2f(v1.z); a3 += bf2f(v0.w) + bf2f(v1.w);
    }
    if (j < end) {
        ushort4 v0 = *(const ushort4*)(X + (size_t)eidx[j] * 256 + lane * 4);
        a0 += bf2f(v0.x); a1 += bf2f(v0.y); a2 += bf2f(v0.z); a3 += bf2f(v0.w);
    }
    const float sc = 1.0f / fmaxf((float)(end - beg), 1.0f);
    short4 o;
    o.x = f2bf(a0 * sc); o.y = f2bf(a1 * sc);
    o.z = f2bf(a2 * sc); o.w = f2bf(a3 * sc);
    *(short4*)(Acat + (size_t)wv * 512 + lane * 4) = o;
}

// ---------------------------------------------------------------------------
// Layer-1 MFMA GEMM: out[M][256] = Acat1[M][512] @ Wcat1[256][512]^T + bias.
// Block = 4 waves; wave w rows [bx*64+w*16,+16); 4 col-tiles at by*64.
// ---------------------------------------------------------------------------
__global__ __launch_bounds__(256)
void mfma_gemm1_kernel(const short* __restrict__ A, const short* __restrict__ W,
                       const float* __restrict__ bias, float* __restrict__ out) {
    const int tid = threadIdx.x;
    const int wave = tid >> 6;
    const int lane = tid & 63;
    const int r0 = blockIdx.x * 64 + wave * 16;
    const int j0 = blockIdx.y * 64;
    const int lrow = lane & 15;
    const int lk = (lane >> 4) * 8;

    const short* arow = A + (size_t)(r0 + lrow) * 512 + lk;
    const short* wbase = W + (size_t)(j0 + lrow) * 512 + lk;

    f32x4 acc[4] = {};
#pragma unroll
    for (int ks = 0; ks < 16; ++ks) {
        bf16x8 a = *(const bf16x8*)(arow + ks * 32);
#pragma unroll
        for (int c = 0; c < 4; ++c) {
            bf16x8 b = *(const bf16x8*)(wbase + (size_t)c * 16 * 512 + ks * 32);
            acc[c] = __builtin_amdgcn_mfma_f32_16x16x32_bf16(a, b, acc[c], 0, 0, 0);
        }
    }

    const int orow = (lane >> 4) * 4;
#pragma unroll
    for (int c = 0; c < 4; ++c) {
        const int col = j0 + c * 16 + lrow;
        const float bv = bias[col];
#pragma unroll
        for (int i = 0; i < 4; ++i) {
            const int row = r0 + orow + i;
            out[(size_t)row * 256 + col] = acc[c][i] + bv;
        }
    }
}

// ---------------------------------------------------------------------------
extern "C" void kernel_launch(void* const* d_in, const int* in_sizes, int n_in,
                              void* d_out, int out_size, void* d_ws, size_t ws_size,
                              hipStream_t stream) {
    const float* x    = (const float*)d_in[0];
    const int*   src0 = (const int*)d_in[1];
    const int*   dst0 = (const int*)d_in[2];
    const int*   src1 = (const int*)d_in[3];
    const int*   dst1 = (const int*)d_in[4];
    const float* Wl0  = (const float*)d_in[5];
    const float* bl0  = (const float*)d_in[6];
    const float* Wr0  = (const float*)d_in[7];
    const float* Wl1  = (const float*)d_in[8];
    const float* bl1  = (const float*)d_in[9];
    const float* Wr1  = (const float*)d_in[10];

    const int E0 = in_sizes[1];
    const int E1 = in_sizes[3];

    // workspace layout
    char* p = (char*)d_ws;
    short* h     = (short*)p;            p += (size_t)N1C * 256 * 2;
    short* Acat1 = (short*)p;            p += (size_t)N2C * 512 * 2;
    short* Wcat0 = (short*)p;            p += 256 * 512 * 2;
    short* Wcat1 = (short*)p;            p += 256 * 512 * 2;
    int* hist0   = (int*)p;              p += (size_t)N1C * 4;
    int* cursor0 = (int*)p;              p += (size_t)N1C * 4;
    int* rowptr0 = (int*)p;              p += (size_t)(N1C + 4) * 4;
    int* hist1   = (int*)p;              p += (size_t)N2C * 4;
    int* cursor1 = (int*)p;              p += (size_t)N2C * 4;
    int* rowptr1 = (int*)p;              p += (size_t)(N2C + 4) * 4;
    int* eidx0   = (int*)p;              p += (size_t)E0 * 4;
    int* eidx1   = (int*)p;              p += (size_t)E1 * 4;

    // 1. prep: Wcat bf16 + zero hists
    prep_kernel<<<512, 256, 0, stream>>>(Wl0, Wr0, Wl1, Wr1, Wcat0, Wcat1, hist0, hist1);
    // 2-4. CSR build (both layers)
    hist_both_kernel<<<512, 256, 0, stream>>>(dst0, E0, dst1, E1, hist0, hist1);
    scan_both_kernel<<<2, 1024, 0, stream>>>(hist0, rowptr0, cursor0, hist1, rowptr1, cursor1);
    fill_both_kernel<<<512, 256, 0, stream>>>(src0, dst0, E0, src1, dst1, E1,
                                              cursor0, eidx0, cursor1, eidx1);
    // 5. FUSED layer-0: gather + GEMM -> h (+ Acat1 right half)
    sage0_fused_kernel<<<N1C / 64, 256, 0, stream>>>(x, rowptr0, eidx0, Wcat0, bl0,
                                                     h, Acat1);
    // 6. layer-1 gather-mean (from h) -> Acat1 left half
    gather1_kernel<<<(N2C * 64 + 255) / 256, 256, 0, stream>>>(
        (const ushort*)h, rowptr1, eidx1, Acat1, N2C);
    // 7. layer-1 GEMM -> d_out (fp32)
    mfma_gemm1_kernel<<<dim3(N2C / 64, 4), 256, 0, stream>>>(Acat1, Wcat1, bl1,
                                                             (float*)d_out);
}

// Round 11
// 210.688 us; speedup vs baseline: 1.0939x; 1.0939x over previous
//
#include <hip/hip_runtime.h>
#include <hip/hip_bf16.h>

#define N0C 360448
#define N1C 22528
#define N2C 2048

typedef __attribute__((ext_vector_type(8))) short bf16x8;
typedef __attribute__((ext_vector_type(4))) float f32x4;
typedef __attribute__((ext_vector_type(2))) int i32x2;

__device__ __forceinline__ short f2bf(float f) {
    union { float f; unsigned u; } x; x.f = f;
    unsigned r = x.u + 0x7fff + ((x.u >> 16) & 1);   // RNE
    return (short)(r >> 16);
}
__device__ __forceinline__ float bf2f(unsigned short u) {
    union { unsigned u; float f; } x; x.u = ((unsigned)u) << 16;
    return x.f;
}

// ---------------------------------------------------------------------------
// Prep: Wcat{0,1} bf16 [256][512] = [Wl | Wr] rows; zero hists.
// ---------------------------------------------------------------------------
__global__ __launch_bounds__(256)
void prep_kernel(const float* __restrict__ Wl0, const float* __restrict__ Wr0,
                 const float* __restrict__ Wl1, const float* __restrict__ Wr1,
                 short* __restrict__ Wcat0, short* __restrict__ Wcat1,
                 int* __restrict__ hist0, int* __restrict__ hist1) {
    const int stride = gridDim.x * blockDim.x;
    const int t0 = blockIdx.x * blockDim.x + threadIdx.x;
    for (int i = t0; i < 2 * 256 * 512; i += stride) {
        int layer = i >> 17;
        int r = i & ((1 << 17) - 1);
        int j = r >> 9, k = r & 511;
        const float* Wl = layer ? Wl1 : Wl0;
        const float* Wr = layer ? Wr1 : Wr0;
        float v = (k < 256) ? Wl[j * 256 + k] : Wr[j * 256 + (k - 256)];
        (layer ? Wcat1 : Wcat0)[r] = f2bf(v);
    }
    for (int i = t0; i < N1C + N2C; i += stride) {
        if (i < N1C) hist0[i] = 0; else hist1[i - N1C] = 0;
    }
}

// ---------------------------------------------------------------------------
// CSR build (both layers)
// ---------------------------------------------------------------------------
__global__ void hist_both_kernel(const int* __restrict__ dst0, int E0,
                                 const int* __restrict__ dst1, int E1,
                                 int* __restrict__ hist0, int* __restrict__ hist1) {
    const int stride = gridDim.x * blockDim.x;
    for (int i = blockIdx.x * blockDim.x + threadIdx.x; i < E0 + E1; i += stride) {
        if (i < E0) atomicAdd(&hist0[dst0[i]], 1);
        else        atomicAdd(&hist1[dst1[i - E0]], 1);
    }
}

// Shuffle-based single-block scan: 2 barriers total.
__global__ __launch_bounds__(1024)
void scan_both_kernel(const int* __restrict__ hist0, int* __restrict__ rowptr0,
                      int* __restrict__ cursor0,
                      const int* __restrict__ hist1, int* __restrict__ rowptr1,
                      int* __restrict__ cursor1) {
    __shared__ int wsum[16];
    const int N = (blockIdx.x == 0) ? N1C : N2C;
    const int* hist   = (blockIdx.x == 0) ? hist0 : hist1;
    int* rowptr       = (blockIdx.x == 0) ? rowptr0 : rowptr1;
    int* cursor       = (blockIdx.x == 0) ? cursor0 : cursor1;
    const int tid = threadIdx.x;
    const int lane = tid & 63;
    const int wid = tid >> 6;
    const int per = (N + 1023) >> 10;
    const int start = min(tid * per, N);
    const int end = min(start + per, N);
    int s = 0;
    for (int i = start; i < end; ++i) s += hist[i];
    int incl = s;
#pragma unroll
    for (int d = 1; d < 64; d <<= 1) {
        int t = __shfl_up(incl, d);
        if (lane >= d) incl += t;
    }
    if (lane == 63) wsum[wid] = incl;
    __syncthreads();
    if (wid == 0) {
        int v = (lane < 16) ? wsum[lane] : 0;
#pragma unroll
        for (int d = 1; d < 16; d <<= 1) {
            int t = __shfl_up(v, d);
            if (lane >= d) v += t;
        }
        if (lane < 16) wsum[lane] = v;
    }
    __syncthreads();
    int off = (wid > 0 ? wsum[wid - 1] : 0) + (incl - s);   // exclusive prefix
    for (int i = start; i < end; ++i) {
        rowptr[i] = off;
        cursor[i] = off;
        off += hist[i];
    }
    if (tid == 1023) rowptr[N] = wsum[15];
}

__global__ void fill_both_kernel(const int* __restrict__ src0, const int* __restrict__ dst0, int E0,
                                 const int* __restrict__ src1, const int* __restrict__ dst1, int E1,
                                 int* __restrict__ cursor0, int* __restrict__ eidx0,
                                 int* __restrict__ cursor1, int* __restrict__ eidx1) {
    const int stride = gridDim.x * blockDim.x;
    for (int i = blockIdx.x * blockDim.x + threadIdx.x; i < E0 + E1; i += stride) {
        if (i < E0) {
            int p = atomicAdd(&cursor0[dst0[i]], 1);
            eidx0[p] = src0[i];
        } else {
            int p = atomicAdd(&cursor1[dst1[i - E0]], 1);
            eidx1[p] = src1[i - E0];
        }
    }
}

// ---------------------------------------------------------------------------
// Layer-0 fused gather + xcast (fp32 source, normal loads, 8-deep unroll):
//   Acat0[wv][0:256)   = mean of x[eidx[rowptr[wv]..rowptr[wv+1])]
//   Acat0[wv][256:512) = x[wv] (bf16)
// Acat0 stores are NONTEMPORAL: keep scratch out of L3 so x stays resident.
// ---------------------------------------------------------------------------
__global__ __launch_bounds__(256)
void gather0_kernel(const float* __restrict__ x, const int* __restrict__ rowptr,
                    const int* __restrict__ eidx, short* __restrict__ Acat0) {
    const int wv = (blockIdx.x * 256 + threadIdx.x) >> 6;
    const int lane = threadIdx.x & 63;
    if (wv >= N1C) return;
    const int co = lane * 4;

    const float4 xr = *(const float4*)(x + (size_t)wv * 256 + co);

    const int beg = rowptr[wv];
    const int end = rowptr[wv + 1];
    f32x4 acc = {0.f, 0.f, 0.f, 0.f};
    f32x4 acc2 = {0.f, 0.f, 0.f, 0.f};
    int j = beg;
    for (; j + 7 < end; j += 8) {
        const f32x4 v0 = *(const f32x4*)(x + (size_t)eidx[j    ] * 256 + co);
        const f32x4 v1 = *(const f32x4*)(x + (size_t)eidx[j + 1] * 256 + co);
        const f32x4 v2 = *(const f32x4*)(x + (size_t)eidx[j + 2] * 256 + co);
        const f32x4 v3 = *(const f32x4*)(x + (size_t)eidx[j + 3] * 256 + co);
        const f32x4 v4 = *(const f32x4*)(x + (size_t)eidx[j + 4] * 256 + co);
        const f32x4 v5 = *(const f32x4*)(x + (size_t)eidx[j + 5] * 256 + co);
        const f32x4 v6 = *(const f32x4*)(x + (size_t)eidx[j + 6] * 256 + co);
        const f32x4 v7 = *(const f32x4*)(x + (size_t)eidx[j + 7] * 256 + co);
        acc  += v0 + v1 + v2 + v3;
        acc2 += v4 + v5 + v6 + v7;
    }
    for (; j + 1 < end; j += 2) {
        const f32x4 v0 = *(const f32x4*)(x + (size_t)eidx[j    ] * 256 + co);
        const f32x4 v1 = *(const f32x4*)(x + (size_t)eidx[j + 1] * 256 + co);
        acc += v0 + v1;
    }
    if (j < end)
        acc2 += *(const f32x4*)(x + (size_t)eidx[j] * 256 + co);
    acc += acc2;

    const float sc = 1.0f / fmaxf((float)(end - beg), 1.0f);
    union { short s[4]; i32x2 i; } o;
    o.s[0] = f2bf(acc.x * sc); o.s[1] = f2bf(acc.y * sc);
    o.s[2] = f2bf(acc.z * sc); o.s[3] = f2bf(acc.w * sc);
    __builtin_nontemporal_store(o.i, (i32x2*)(Acat0 + (size_t)wv * 512 + co));

    union { short s[4]; i32x2 i; } xo;
    xo.s[0] = f2bf(xr.x); xo.s[1] = f2bf(xr.y);
    xo.s[2] = f2bf(xr.z); xo.s[3] = f2bf(xr.w);
    __builtin_nontemporal_store(xo.i, (i32x2*)(Acat0 + (size_t)wv * 512 + 256 + co));
}

// ---------------------------------------------------------------------------
// Layer-1 gather-mean from bf16 h -> left half of Acat1. (2048 waves)
// ---------------------------------------------------------------------------
__global__ __launch_bounds__(256)
void gather1_kernel(const ushort* __restrict__ X, const int* __restrict__ rowptr,
                    const int* __restrict__ eidx, short* __restrict__ Acat, int N) {
    const int wv = (blockIdx.x * 256 + threadIdx.x) >> 6;
    const int lane = threadIdx.x & 63;
    if (wv >= N) return;
    const int beg = rowptr[wv];
    const int end = rowptr[wv + 1];
    float a0 = 0.f, a1 = 0.f, a2 = 0.f, a3 = 0.f;
    int j = beg;
    for (; j + 1 < end; j += 2) {
        int s0 = eidx[j], s1 = eidx[j + 1];
        ushort4 v0 = *(const ushort4*)(X + (size_t)s0 * 256 + lane * 4);
        ushort4 v1 = *(const ushort4*)(X + (size_t)s1 * 256 + lane * 4);
        a0 += bf2f(v0.x) + bf2f(v1.x); a1 += bf2f(v0.y) + bf2f(v1.y);
        a2 += bf2f(v0.z) + bf2f(v1.z); a3 += bf2f(v0.w) + bf2f(v1.w);
    }
    if (j < end) {
        ushort4 v0 = *(const ushort4*)(X + (size_t)eidx[j] * 256 + lane * 4);
        a0 += bf2f(v0.x); a1 += bf2f(v0.y); a2 += bf2f(v0.z); a3 += bf2f(v0.w);
    }
    const float sc = 1.0f / fmaxf((float)(end - beg), 1.0f);
    short4 o;
    o.x = f2bf(a0 * sc); o.y = f2bf(a1 * sc);
    o.z = f2bf(a2 * sc); o.w = f2bf(a3 * sc);
    *(short4*)(Acat + (size_t)wv * 512 + lane * 4) = o;
}

// ---------------------------------------------------------------------------
// MFMA GEMM: C[M][256] = Acat[M][512] @ Wcat[256][512]^T + bias, opt. ReLU.
// Block = 4 waves; wave w rows [bx*64+w*16,+16); CT col-tiles at by*CT*16.
// OUT_BF16: also dual-write first N2C rows into out2 right half (Acat1).
// ---------------------------------------------------------------------------
template <int CT, bool RELU, bool OUT_BF16>
__global__ __launch_bounds__(256)
void mfma_gemm_kernel(const short* __restrict__ A, const short* __restrict__ W,
                      const float* __restrict__ bias, void* __restrict__ out,
                      short* __restrict__ out2, int M) {
    const int tid = threadIdx.x;
    const int wave = tid >> 6;
    const int lane = tid & 63;
    const int r0 = blockIdx.x * 64 + wave * 16;
    const int j0 = blockIdx.y * (CT * 16);
    const int lrow = lane & 15;
    const int lk = (lane >> 4) * 8;

    const short* arow = A + (size_t)(r0 + lrow) * 512 + lk;
    const short* wbase = W + (size_t)(j0 + lrow) * 512 + lk;

    f32x4 acc[CT] = {};
#pragma unroll
    for (int ks = 0; ks < 16; ++ks) {
        bf16x8 a = *(const bf16x8*)(arow + ks * 32);
#pragma unroll
        for (int c = 0; c < CT; ++c) {
            bf16x8 b = *(const bf16x8*)(wbase + (size_t)c * 16 * 512 + ks * 32);
            acc[c] = __builtin_amdgcn_mfma_f32_16x16x32_bf16(a, b, acc[c], 0, 0, 0);
        }
    }

    const int orow = (lane >> 4) * 4;
#pragma unroll
    for (int c = 0; c < CT; ++c) {
        const int col = j0 + c * 16 + lrow;
        const float bv = bias[col];
#pragma unroll
        for (int i = 0; i < 4; ++i) {
            const int row = r0 + orow + i;
            float v = acc[c][i] + bv;
            if (RELU) v = fmaxf(v, 0.0f);
            if (OUT_BF16) {
                short hv = f2bf(v);
                ((short*)out)[(size_t)row * 256 + col] = hv;
                if (out2 != nullptr && row < N2C)
                    out2[(size_t)row * 512 + 256 + col] = hv;
            } else {
                ((float*)out)[(size_t)row * 256 + col] = v;
            }
        }
    }
}

// ---------------------------------------------------------------------------
extern "C" void kernel_launch(void* const* d_in, const int* in_sizes, int n_in,
                              void* d_out, int out_size, void* d_ws, size_t ws_size,
                              hipStream_t stream) {
    const float* x    = (const float*)d_in[0];
    const int*   src0 = (const int*)d_in[1];
    const int*   dst0 = (const int*)d_in[2];
    const int*   src1 = (const int*)d_in[3];
    const int*   dst1 = (const int*)d_in[4];
    const float* Wl0  = (const float*)d_in[5];
    const float* bl0  = (const float*)d_in[6];
    const float* Wr0  = (const float*)d_in[7];
    const float* Wl1  = (const float*)d_in[8];
    const float* bl1  = (const float*)d_in[9];
    const float* Wr1  = (const float*)d_in[10];

    const int E0 = in_sizes[1];
    const int E1 = in_sizes[3];

    // workspace layout
    char* p = (char*)d_ws;
    short* Acat0 = (short*)p;            p += (size_t)N1C * 512 * 2;
    short* h     = (short*)p;            p += (size_t)N1C * 256 * 2;
    short* Acat1 = (short*)p;            p += (size_t)N2C * 512 * 2;
    short* Wcat0 = (short*)p;            p += 256 * 512 * 2;
    short* Wcat1 = (short*)p;            p += 256 * 512 * 2;
    int* hist0   = (int*)p;              p += (size_t)N1C * 4;
    int* cursor0 = (int*)p;              p += (size_t)N1C * 4;
    int* rowptr0 = (int*)p;              p += (size_t)(N1C + 4) * 4;
    int* hist1   = (int*)p;              p += (size_t)N2C * 4;
    int* cursor1 = (int*)p;              p += (size_t)N2C * 4;
    int* rowptr1 = (int*)p;              p += (size_t)(N2C + 4) * 4;
    int* eidx0   = (int*)p;              p += (size_t)E0 * 4;
    int* eidx1   = (int*)p;              p += (size_t)E1 * 4;

    // 1. prep: Wcat bf16 + zero hists
    prep_kernel<<<512, 256, 0, stream>>>(Wl0, Wr0, Wl1, Wr1, Wcat0, Wcat1, hist0, hist1);
    // 2-4. CSR build (both layers)
    hist_both_kernel<<<512, 256, 0, stream>>>(dst0, E0, dst1, E1, hist0, hist1);
    scan_both_kernel<<<2, 1024, 0, stream>>>(hist0, rowptr0, cursor0, hist1, rowptr1, cursor1);
    fill_both_kernel<<<512, 256, 0, stream>>>(src0, dst0, E0, src1, dst1, E1,
                                              cursor0, eidx0, cursor1, eidx1);
    // 5. layer-0 fused gather-mean + xcast -> Acat0 (nt stores)
    gather0_kernel<<<(N1C * 64 + 255) / 256, 256, 0, stream>>>(x, rowptr0, eidx0, Acat0);
    // 6. layer-0 GEMM (CT=8, 2 col-passes) -> h (bf16) + Acat1 right half
    mfma_gemm_kernel<8, true, true><<<dim3(N1C / 64, 2), 256, 0, stream>>>(
        Acat0, Wcat0, bl0, h, Acat1, N1C);
    // 7. layer-1 gather-mean (from h) -> Acat1 left half
    gather1_kernel<<<(N2C * 64 + 255) / 256, 256, 0, stream>>>(
        (const ushort*)h, rowptr1, eidx1, Acat1, N2C);
    // 8. layer-1 GEMM (CT=2, 8 col-passes -> 256 blocks) -> d_out (fp32)
    mfma_gemm_kernel<2, false, false><<<dim3(N2C / 64, 8), 256, 0, stream>>>(
        Acat1, Wcat1, bl1, (float*)d_out, nullptr, N2C);
}